// Round 3
// baseline (1143.478 us; speedup 1.0000x reference)
//
#include <hip/hip_runtime.h>
#include <hip/hip_bf16.h>

// Problem sizes (fixed by reference):
// x: (16, 528, 32, 28, 28) fp32; bbox: (256,5); w1:(128,528); w2:(32,128); w3:(1,32)
// out: 256 fp32
#define BB 16
#define CC 528
#define TT 32
#define HW 784        // 28*28
#define NJ 128
#define NROI 256
#define CL 8          // channel chunk; 528 = 66*8
#define NCHUNK 66
#define TILE 49       // 784 = 16*49 -> grid 16x16 = 256 blocks = 1 per CU
#define FSROW 52      // padded row (52*4 B = 208 B, 16-B aligned rows)
#define NSTAGE 392    // CL*TILE staging threads (of 448)

// ---------------- Kernel T: w1T[c][j] = w1[j][c] (one-shot, tiny) ----------------
__global__ void transpose_w1(const float* __restrict__ w1, float* __restrict__ w1T) {
    int c = blockIdx.x;       // 528
    int j = threadIdx.x;      // 128
    w1T[c * NJ + j] = w1[j * CC + c];
}

// ---------------- Fused kernel: g[b,p,j] = sum_c w1[j,c] * mean_t x[b,c,t,p] ----------------
// grid (16, 16): px tile of 49 (contiguous), batch b. block 448 = 7 waves.
// Staging role (tid<392): (cl = tid/49, px = tid%49); sums 32 t's in regs (software-pipelined).
// Compute role: jg = tid&31 (4 j's), pr = tid>>5 in [0,14) (4 px's, masked at 49) -> acc[4][4].
__global__ __launch_bounds__(448) void fused_proj_kernel(const float* __restrict__ x,
                                                         const float* __restrict__ w1T,
                                                         float* __restrict__ g) {
    __shared__ __align__(16) float fs[2][CL * FSROW + 16];  // padded: OOB-safe tail reads
    __shared__ __align__(16) float w1s[2][CL * NJ];         // 2 x 1024
    const int tile = blockIdx.x;   // 0..15
    const int b    = blockIdx.y;   // 0..15
    const int tid  = threadIdx.x;
    const bool stager = tid < NSTAGE;
    const int cl   = tid / TILE;   // 0..7 (stagers)
    const int px   = tid - cl * TILE;
    const int p0   = tile * TILE;
    const int jg   = tid & 31;     // j = 4*jg..4*jg+3
    const int pr   = tid >> 5;     // 0..13 -> px = 4*pr..4*pr+3 (masked vs 49)

    const float* xb = x + ((size_t)b * CC + cl) * (size_t)(TT * HW) + p0 + px;

    float acc[4][4];
#pragma unroll
    for (int a = 0; a < 4; ++a)
#pragma unroll
        for (int i = 0; i < 4; ++i) acc[a][i] = 0.f;

    // ---- prologue: load chunk 0 into registers, store to buf 0 ----
    float tv[TT];
    if (stager) {
#pragma unroll
        for (int t = 0; t < TT; ++t) tv[t] = xb[t * HW];
    }
    float wa = w1T[tid];
    float wb = w1T[448 + tid];
    float wc = (tid < 128) ? w1T[896 + tid] : 0.f;
    {
        if (stager) {
            float s = 0.f;
#pragma unroll
            for (int t = 0; t < TT; ++t) s += tv[t];
            fs[0][cl * FSROW + px] = s * 0.03125f;
        }
        w1s[0][tid] = wa;
        w1s[0][448 + tid] = wb;
        if (tid < 128) w1s[0][896 + tid] = wc;
    }
    __syncthreads();

    for (int ch = 0; ch < NCHUNK; ++ch) {
        const int nxt = ch + 1;
        // ---- issue next chunk's loads (stay in flight during compute) ----
        if (nxt < NCHUNK) {
            if (stager) {
                const float* xq = xb + (size_t)nxt * (CL * TT * HW);
#pragma unroll
                for (int t = 0; t < TT; ++t) tv[t] = xq[t * HW];
            }
            const float* wq = w1T + nxt * (CL * NJ);
            wa = wq[tid];
            wb = wq[448 + tid];
            if (tid < 128) wc = wq[896 + tid];
        }
        // ---- compute chunk ch from buf (ch&1) ----
        const float* fsb = fs[ch & 1];
        const float* wsb = w1s[ch & 1];
#pragma unroll
        for (int c = 0; c < CL; ++c) {
            float4 wv = *(const float4*)&wsb[c * NJ + jg * 4];    // b128, conflict-free
            float4 fv = *(const float4*)&fsb[c * FSROW + pr * 4]; // b128, 2-addr broadcast
            acc[0][0] += wv.x * fv.x; acc[0][1] += wv.x * fv.y; acc[0][2] += wv.x * fv.z; acc[0][3] += wv.x * fv.w;
            acc[1][0] += wv.y * fv.x; acc[1][1] += wv.y * fv.y; acc[1][2] += wv.y * fv.z; acc[1][3] += wv.y * fv.w;
            acc[2][0] += wv.z * fv.x; acc[2][1] += wv.z * fv.y; acc[2][2] += wv.z * fv.z; acc[2][3] += wv.z * fv.w;
            acc[3][0] += wv.w * fv.x; acc[3][1] += wv.w * fv.y; acc[3][2] += wv.w * fv.z; acc[3][3] += wv.w * fv.w;
        }
        // ---- reduce+store next chunk into the other buffer (waits on vmcnt here) ----
        if (nxt < NCHUNK) {
            float* fw = fs[nxt & 1];
            float* ww = w1s[nxt & 1];
            if (stager) {
                float s = 0.f;
#pragma unroll
                for (int t = 0; t < TT; ++t) s += tv[t];
                fw[cl * FSROW + px] = s * 0.03125f;
            }
            ww[tid] = wa;
            ww[448 + tid] = wb;
            if (tid < 128) ww[896 + tid] = wc;
        }
        __syncthreads();   // one barrier per chunk (ping-pong makes it sufficient)
    }

    // ---- write g: up to 4 px x float4 of j, coalesced; mask the 49-tail ----
#pragma unroll
    for (int i = 0; i < 4; ++i) {
        int pxi = pr * 4 + i;
        if (pxi < TILE) {
            float4 o;
            o.x = acc[0][i]; o.y = acc[1][i]; o.z = acc[2][i]; o.w = acc[3][i];
            *(float4*)(g + ((size_t)(b * HW + p0 + pxi)) * NJ + jg * 4) = o;
        }
    }
}

// ---------------- Kernel C: per-ROI bilinear pooling on g + MLP ----------------
__global__ __launch_bounds__(256) void roi_mlp_kernel(const float* __restrict__ g,
                                                      const float* __restrict__ bbox,
                                                      const float* __restrict__ b1,
                                                      const float* __restrict__ w2,
                                                      const float* __restrict__ b2,
                                                      const float* __restrict__ w3,
                                                      const float* __restrict__ b3,
                                                      float* __restrict__ out) {
    __shared__ float red[2][NJ];
    __shared__ float h1s[NJ];
    __shared__ float h2s[32];
    __shared__ float w2s[32 * 129];  // padded stride to avoid bank conflicts
    int r = blockIdx.x;
    int tid = threadIdx.x;

    // stage w2 (coalesced global read, padded LDS write)
    for (int t = tid; t < 32 * NJ; t += 256) {
        w2s[(t >> 7) * 129 + (t & 127)] = w2[t];
    }

    int b = (int)bbox[5 * r];
    float x1 = bbox[5 * r + 1] * 0.0625f - 0.5f;
    float y1 = bbox[5 * r + 2] * 0.0625f - 0.5f;
    float x2 = bbox[5 * r + 3] * 0.0625f - 0.5f;
    float y2 = bbox[5 * r + 4] * 0.0625f - 0.5f;
    float bw = (x2 - x1) * 0.125f;  // /OUT
    float bh = (y2 - y1) * 0.125f;

    int j = tid & 127;
    int grp = tid >> 7;  // 2 sample groups
    const float* gb = g + (size_t)b * HW * NJ;
    float acc = 0.f;

    for (int s = grp; s < 256; s += 2) {
        int iy = s >> 4, ix = s & 15;
        float yy = y1 + (iy + 0.5f) * 0.5f * bh;   // off=(iy+0.5)/SR
        float xx = x1 + (ix + 0.5f) * 0.5f * bw;
        if (yy > -1.f && yy < 28.f && xx > -1.f && xx < 28.f) {
            float yc = fminf(fmaxf(yy, 0.f), 27.f);
            float xc = fminf(fmaxf(xx, 0.f), 27.f);
            int y0 = (int)floorf(yc);
            int x0 = (int)floorf(xc);
            int y1i = min(y0 + 1, 27);
            int x1i = min(x0 + 1, 27);
            float ly = yc - (float)y0, lx = xc - (float)x0;
            float hy = 1.f - ly, hx = 1.f - lx;
            const float* r0 = gb + (size_t)(y0 * 28) * NJ;
            const float* r1p = gb + (size_t)(y1i * 28) * NJ;
            float v00 = r0[x0 * NJ + j];
            float v01 = r0[x1i * NJ + j];
            float v10 = r1p[x0 * NJ + j];
            float v11 = r1p[x1i * NJ + j];
            acc += hy * hx * v00 + hy * lx * v01 + ly * hx * v10 + ly * lx * v11;
        }
    }
    red[grp][j] = acc;
    __syncthreads();
    if (tid < NJ) {
        float tot = (red[0][tid] + red[1][tid]) * (1.f / 256.f) + b1[tid];
        h1s[tid] = fmaxf(tot, 0.f);
    }
    __syncthreads();
    if (tid < 32) {
        float a2 = b2[tid];
#pragma unroll 8
        for (int jj = 0; jj < NJ; ++jj) a2 += w2s[tid * 129 + jj] * h1s[jj];
        h2s[tid] = a2;
    }
    __syncthreads();
    if (tid == 0) {
        float o = b3[0];
#pragma unroll
        for (int k = 0; k < 32; ++k) o += w3[k] * h2s[k];
        out[r] = o;
    }
}

extern "C" void kernel_launch(void* const* d_in, const int* in_sizes, int n_in,
                              void* d_out, int out_size, void* d_ws, size_t ws_size,
                              hipStream_t stream) {
    (void)in_sizes; (void)n_in; (void)out_size; (void)ws_size;
    const float* x    = (const float*)d_in[0];
    const float* bbox = (const float*)d_in[1];
    const float* w1   = (const float*)d_in[2];
    const float* b1   = (const float*)d_in[3];
    const float* w2   = (const float*)d_in[4];
    const float* b2   = (const float*)d_in[5];
    const float* w3   = (const float*)d_in[6];
    const float* b3   = (const float*)d_in[7];
    float* out = (float*)d_out;

    float* g   = (float*)d_ws;                 // 16*784*128 = 1,605,632 floats (6.4 MB)
    float* w1T = g + (size_t)BB * HW * NJ;     // 528*128    =    67,584 floats

    transpose_w1<<<CC, NJ, 0, stream>>>(w1, w1T);
    fused_proj_kernel<<<dim3(16, BB), 448, 0, stream>>>(x, w1T, g);
    roi_mlp_kernel<<<NROI, 256, 0, stream>>>(g, bbox, b1, w2, b2, w3, b3, out);
}